// Round 2
// baseline (56.845 us; speedup 1.0000x reference)
//
#include <hip/hip_runtime.h>
#include <math.h>

#define NA 512
#define NQC 8
#define SRC_STRIDE 12   // floats per (i,q) packed record (3 x float4)
#define NHALF 2         // i-range split per receiver j
#define IPB (NA / NHALF) // 256 i per block

#define NCf ((float)(90.4756 / 6.28318530717958647692))
#define A_ERF 0.70710678118654752f      // 1/sqrt(2)
#define G_COEF 0.79788456080286536f     // sqrt(2/pi)

// ---------------- pack kernel: per-(i,q) moments + r as float4 ----------------
__global__ void pack_kernel(const float* __restrict__ q,
                            const float* __restrict__ r,
                            const float* __restrict__ u,
                            const float* __restrict__ quad,
                            float* __restrict__ ws_src,
                            float4* __restrict__ ws_r4) {
    int idx = blockIdx.x * blockDim.x + threadIdx.x;   // 0..4095
    if (idx < NA) {
        ws_r4[idx] = make_float4(r[idx*3+0], r[idx*3+1], r[idx*3+2], 0.0f);
    }
    if (idx >= NA * NQC) return;
    const float* Q = quad + (size_t)idx * 9;
    float xx = Q[0], yy = Q[4], zz = Q[8];
    float xy = 0.5f * (Q[1] + Q[3]);
    float xz = 0.5f * (Q[2] + Q[6]);
    float yz = 0.5f * (Q[5] + Q[7]);
    float tq = xx + yy + zz;
    float* s = ws_src + (size_t)idx * SRC_STRIDE;
    s[0]  = q[idx];
    s[1]  = tq;
    s[2]  = u[idx*3+0];
    s[3]  = u[idx*3+1];
    s[4]  = u[idx*3+2];
    s[5]  = xx; s[6] = yy; s[7] = zz;
    s[8]  = xy; s[9] = xz; s[10] = yz;
    s[11] = 0.0f;
}

// ---------------- main kernel ----------------
// grid = NA*NHALF blocks; block b handles receiver j = b>>1, i-range half = b&1
// block = 256 threads: qch = tid&7, seg = tid>>3 (each seg covers 8 local i's)
// Phase 1: each thread computes pair coefficients c0..c4 + d for ONE pair -> LDS
// Phase 2: per-channel contraction reading coefficients from LDS (broadcast)
__global__ __launch_bounds__(256, 4)
void main2_kernel(const float* __restrict__ ws_src,
                  const float4* __restrict__ r4,
                  float* __restrict__ part) {
    const int b    = blockIdx.x;
    const int j    = b >> 1;
    const int half = b & 1;
    const int tid  = threadIdx.x;
    const int qch  = tid & 7;
    const int seg  = tid >> 3;   // 0..31

    __shared__ float co[IPB][9];      // c0..c4, dx,dy,dz (stride 9: 2-way bank alias only)
    __shared__ float red[4][8][9];

    // ---- phase 1: pair coefficients (one pair per thread) ----
    {
        const int i = half * IPB + tid;
        const float4 ri = r4[i];
        const float4 rj = r4[j];
        float dx = rj.x - ri.x, dy = rj.y - ri.y, dz = rj.z - ri.z;
        float r2 = dx*dx + dy*dy + dz*dz;
        const bool diag = (i == j);
        if (diag) r2 = 1.0f;
        const float ir  = rsqrtf(r2);
        const float rr  = r2 * ir;
        const float E   = erff(A_ERF * rr);
        const float G   = G_COEF * __expf(-0.5f * r2);
        const float ir2 = ir * ir;
        const float ir4 = ir2 * ir2;
        const float g   = E * ir;
        const float GmG = G - g;
        const float nco = diag ? 0.0f : NCf;
        co[tid][0] = nco * g;
        co[tid][1] = nco * ir2 * GmG;
        co[tid][2] = nco * ir2 * (-3.0f*ir2*GmG - G);
        co[tid][3] = nco * ir2 * (15.0f*ir4*GmG + 5.0f*G*ir2 + G);
        co[tid][4] = nco * ir2 * (-105.0f*ir4*ir2*GmG - 35.0f*G*ir4 - 7.0f*G*ir2 - G);
        co[tid][5] = dx; co[tid][6] = dy; co[tid][7] = dz;
    }

    // receiver symmetric quadrupole (per-channel), from packed records
    const int jq = j * NQC + qch;
    const float4* sj4 = (const float4*)(ws_src + (size_t)jq * SRC_STRIDE);
    const float4 sja = sj4[0], sjb = sj4[1], sjc = sj4[2];
    const float jtq = sja.y;
    const float jxx = sjb.y, jyy = sjb.z, jzz = sjb.w;
    const float jxy = sjc.x, jxz = sjc.y, jyz = sjc.z;

    __syncthreads();

    float e0 = 0.f, eph = 0.f;
    float Fx = 0.f, Fy = 0.f, Fz = 0.f;
    float Hx = 0.f, Hy = 0.f, Hz = 0.f;
    float pQQ = 0.f;

    #pragma unroll
    for (int k = 0; k < 8; ++k) {
        const int il = seg * 8 + k;
        const float c0 = co[il][0], c1 = co[il][1], c2 = co[il][2];
        const float c3 = co[il][3], c4 = co[il][4];
        const float dx = co[il][5], dy = co[il][6], dz = co[il][7];

        const float4* s4 = (const float4*)(ws_src +
            (size_t)((half*IPB + il) * NQC + qch) * SRC_STRIDE);
        const float4 ma = s4[0], mb = s4[1], mc = s4[2];
        const float qi = ma.x, tqi = ma.y, ux = ma.z, uy = ma.w;
        const float uz = mb.x, xx = mb.y, yy = mb.z, zz = mb.w;
        const float xy = mc.x, xz = mc.y, yz = mc.z;

        const float ud  = ux*dx + uy*dy + uz*dz;
        const float Pdx = xx*dx + xy*dy + xz*dz;
        const float Pdy = xy*dx + yy*dy + yz*dz;
        const float Pdz = xz*dx + yz*dy + zz*dz;
        const float Pdd = Pdx*dx + Pdy*dy + Pdz*dz;

        const float t0 = c0 * qi;
        e0  += t0;
        eph += t0 - c1*ud + 0.5f*(c2*Pdd + c1*tqi);

        const float cH = 0.5f*(c2*(ud - tqi) - c3*Pdd);
        const float cF = cH + 0.5f*c2*ud - c1*qi;
        const float c1h = 0.5f * c1;
        Fx += cF*dx + c1*ux - c2*Pdx;
        Fy += cF*dy + c1*uy - c2*Pdy;
        Fz += cF*dz + c1*uz - c2*Pdz;
        Hx += cH*dx + c1h*ux - c2*Pdx;
        Hy += cH*dy + c1h*uy - c2*Pdy;
        Hz += cH*dz + c1h*uz - c2*Pdz;

        const float Rdx = jxx*dx + jxy*dy + jxz*dz;
        const float Rdy = jxy*dx + jyy*dy + jyz*dz;
        const float Rdz = jxz*dx + jyz*dy + jzz*dz;
        const float Rdd = Rdx*dx + Rdy*dy + Rdz*dz;
        const float dPR = Pdx*Rdx + Pdy*Rdy + Pdz*Rdz;
        const float frob = xx*jxx + yy*jyy + zz*jzz + 2.0f*(xy*jxy + xz*jxz + yz*jyz);
        pQQ += c4*(Pdd*Rdd)
             + c3*(jtq*Pdd + tqi*Rdd + 4.0f*dPR)
             + c2*(tqi*jtq + 2.0f*frob);
    }

    // ---- reduction over segments ----
    float acc[9] = {e0, eph, Fx, Fy, Fz, Hx, Hy, Hz, pQQ};
    #pragma unroll
    for (int off = 8; off < 64; off <<= 1) {
        #pragma unroll
        for (int c = 0; c < 9; ++c) acc[c] += __shfl_xor(acc[c], off, 64);
    }
    const int lane = tid & 63, wv = tid >> 6;
    if ((lane & 56) == 0) {
        #pragma unroll
        for (int c = 0; c < 9; ++c) red[wv][lane][c] = acc[c];
    }
    __syncthreads();
    if (tid < 8) {
        #pragma unroll
        for (int c = 0; c < 9; ++c) {
            part[((size_t)b * NQC + tid) * 9 + c] =
                red[0][tid][c] + red[1][tid][c] + red[2][tid][c] + red[3][tid][c];
        }
    }
}

// ---------------- finalize: combine halves, outputs, pot ----------------
__global__ void finalize_kernel(const float* __restrict__ part,
                                const float* __restrict__ qarr,
                                const float* __restrict__ uarr,
                                const float* __restrict__ kaparr,
                                const float* __restrict__ alparr,
                                float* __restrict__ out) {
    const int tid = threadIdx.x;   // 512 threads, 1 block
    float pot = 0.f;
    #pragma unroll
    for (int rec = 0; rec < 8; ++rec) {
        const int jq = rec * 512 + tid;
        const int jj = jq >> 3, qc = jq & 7;
        const float* p0 = part + ((size_t)(jj*2 + 0) * NQC + qc) * 9;
        const float* p1 = part + ((size_t)(jj*2 + 1) * NQC + qc) * 9;
        float v[9];
        #pragma unroll
        for (int c = 0; c < 9; ++c) v[c] = p0[c] + p1[c];
        const float te0 = v[0], teph = v[1];
        const float tFx = v[2], tFy = v[3], tFz = v[4];
        const float tHx = v[5], tHy = v[6], tHz = v[7];
        const float tQQ = v[8] * 0.125f;
        const float qj  = qarr[jq];
        const float ujx = uarr[jq*3+0], ujy = uarr[jq*3+1], ujz = uarr[jq*3+2];
        const float kapv = kaparr[jq];
        const float alpv = alparr[jq];

        pot += qj * (teph - 0.5f*te0)
             - (ujx*tHx + ujy*tHy + ujz*tHz)
             + tQQ
             - 0.5f * kapv * teph * teph
             - 0.5f * alpv * (tFx*tFx + tFy*tFy + tFz*tFz);

        out[1 + jq] = -kapv * teph;
        out[1 + NA*NQC + jq*3 + 0] = alpv * tFx;
        out[1 + NA*NQC + jq*3 + 1] = alpv * tFy;
        out[1 + NA*NQC + jq*3 + 2] = alpv * tFz;
    }
    // block-level pot reduction (8 waves)
    #pragma unroll
    for (int off = 32; off; off >>= 1) pot += __shfl_xor(pot, off, 64);
    __shared__ float l[8];
    if ((tid & 63) == 0) l[tid >> 6] = pot;
    __syncthreads();
    if (tid == 0) {
        float s = 0.f;
        #pragma unroll
        for (int w = 0; w < 8; ++w) s += l[w];
        out[0] = s;
    }
}

extern "C" void kernel_launch(void* const* d_in, const int* in_sizes, int n_in,
                              void* d_out, int out_size, void* d_ws, size_t ws_size,
                              hipStream_t stream) {
    const float* q    = (const float*)d_in[0];
    const float* r    = (const float*)d_in[1];
    const float* u    = (const float*)d_in[4];
    const float* quad = (const float*)d_in[5];
    const float* kap  = (const float*)d_in[6];
    const float* alp  = (const float*)d_in[7];
    float* out = (float*)d_out;
    float* ws  = (float*)d_ws;

    const size_t src_floats  = (size_t)NA * NQC * SRC_STRIDE;          // 49152
    const size_t r4_floats   = (size_t)NA * 4;                         // 2048
    const size_t part_floats = (size_t)NA * NHALF * NQC * 9;           // 73728

    float*  ws_src = ws;
    float4* r4     = (float4*)(ws + src_floats);
    float*  part   = (float*)(ws + src_floats + r4_floats);
    (void)ws_size; (void)part_floats;

    pack_kernel<<<16, 256, 0, stream>>>(q, r, u, quad, ws_src, r4);
    main2_kernel<<<NA * NHALF, 256, 0, stream>>>(ws_src, r4, part);
    finalize_kernel<<<1, 512, 0, stream>>>(part, q, u, kap, alp, out);
}

// Round 3
// 30.109 us; speedup vs baseline: 1.8880x; 1.8880x over previous
//
#include <hip/hip_runtime.h>
#include <math.h>

#define NA 512
#define NQC 8
#define SRC_STRIDE 12   // floats per (i,q) packed record (3 x float4)

#define NCf ((float)(90.4756 / 6.28318530717958647692))
#define A_ERF 0.70710678118654752f      // 1/sqrt(2)
#define G_COEF 0.79788456080286536f     // sqrt(2/pi)

// ---------------- pack kernel: per-(i,q) moments + r as float4 ----------------
__global__ void pack_kernel(const float* __restrict__ q,
                            const float* __restrict__ r,
                            const float* __restrict__ u,
                            const float* __restrict__ quad,
                            float* __restrict__ ws_src,
                            float4* __restrict__ ws_r4,
                            float* __restrict__ out) {
    int idx = blockIdx.x * blockDim.x + threadIdx.x;   // 0..4095
    if (idx == 0) out[0] = 0.0f;                       // pot accumulator init
    if (idx < NA) {
        ws_r4[idx] = make_float4(r[idx*3+0], r[idx*3+1], r[idx*3+2], 0.0f);
    }
    if (idx >= NA * NQC) return;
    const float* Q = quad + (size_t)idx * 9;
    float xx = Q[0], yy = Q[4], zz = Q[8];
    float xy = 0.5f * (Q[1] + Q[3]);
    float xz = 0.5f * (Q[2] + Q[6]);
    float yz = 0.5f * (Q[5] + Q[7]);
    float tq = xx + yy + zz;
    float* s = ws_src + (size_t)idx * SRC_STRIDE;
    s[0]  = q[idx];
    s[1]  = tq;
    s[2]  = u[idx*3+0];
    s[3]  = u[idx*3+1];
    s[4]  = u[idx*3+2];
    s[5]  = xx; s[6] = yy; s[7] = zz;
    s[8]  = xy; s[9] = xz; s[10] = yz;
    s[11] = 0.0f;
}

// ---------------- main kernel ----------------
// grid = 512 blocks (one receiver j per block), block = 512 threads:
// qch = tid&7 (channel), seg = tid>>3 (0..63), 8 pairs per thread.
// Loop body identical to the proven R1 kernel (per-channel coefficient
// recompute — VALU-cheap, no LDS staging, no min-waves bound).
__global__ __launch_bounds__(512)
void main_kernel(const float* __restrict__ ws_src,
                 const float4* __restrict__ r4,
                 const float* __restrict__ qarr,
                 const float* __restrict__ uarr,
                 const float* __restrict__ kaparr,
                 const float* __restrict__ alparr,
                 float* __restrict__ out) {
    const int j   = blockIdx.x;
    const int tid = threadIdx.x;
    const int qch = tid & 7;
    const int seg = tid >> 3;   // 0..63

    const float4 rj = r4[j];
    const float rjx = rj.x, rjy = rj.y, rjz = rj.z;

    // receiver symmetric quadrupole (per-channel) held across the loop
    const int jq = j * NQC + qch;
    const float4* sj4 = (const float4*)(ws_src + (size_t)jq * SRC_STRIDE);
    const float4 sja = sj4[0], sjb = sj4[1], sjc = sj4[2];
    const float jtq = sja.y;
    const float jxx = sjb.y, jyy = sjb.z, jzz = sjb.w;
    const float jxy = sjc.x, jxz = sjc.y, jyz = sjc.z;

    float e0 = 0.f, eph = 0.f;
    float Fx = 0.f, Fy = 0.f, Fz = 0.f;
    float Hx = 0.f, Hy = 0.f, Hz = 0.f;
    float pQQ = 0.f;

    #pragma unroll 4
    for (int k = 0; k < 8; ++k) {
        const int i = seg * 8 + k;
        const float4 ri = r4[i];
        const float dx = rjx - ri.x, dy = rjy - ri.y, dz = rjz - ri.z;
        float r2 = dx*dx + dy*dy + dz*dz;
        const bool diag = (i == j);
        if (diag) r2 = 1.0f;
        const float ir  = rsqrtf(r2);
        const float rr  = r2 * ir;
        const float E   = erff(A_ERF * rr);
        const float G   = G_COEF * __expf(-0.5f * r2);
        const float ir2 = ir * ir;
        const float ir4 = ir2 * ir2;
        const float g   = E * ir;
        const float GmG = G - g;               // (G - E/r)
        const float nco = diag ? 0.0f : NCf;
        const float c0 = nco * g;
        const float c1 = nco * ir2 * GmG;
        const float c2 = nco * ir2 * (-3.0f*ir2*GmG - G);
        const float c3 = nco * ir2 * (15.0f*ir4*GmG + 5.0f*G*ir2 + G);
        const float c4 = nco * ir2 * (-105.0f*ir4*ir2*GmG - 35.0f*G*ir4 - 7.0f*G*ir2 - G);

        const float4* s4 = (const float4*)(ws_src + (size_t)(i*NQC + qch) * SRC_STRIDE);
        const float4 ma = s4[0], mb = s4[1], mc = s4[2];
        const float qi = ma.x, tqi = ma.y, ux = ma.z, uy = ma.w;
        const float uz = mb.x, xx = mb.y, yy = mb.z, zz = mb.w;
        const float xy = mc.x, xz = mc.y, yz = mc.z;

        const float ud  = ux*dx + uy*dy + uz*dz;
        const float Pdx = xx*dx + xy*dy + xz*dz;
        const float Pdy = xy*dx + yy*dy + yz*dz;
        const float Pdz = xz*dx + yz*dy + zz*dz;
        const float Pdd = Pdx*dx + Pdy*dy + Pdz*dz;

        const float t0 = c0 * qi;
        e0  += t0;
        eph += t0 - c1*ud + 0.5f*(c2*Pdd + c1*tqi);

        const float cH = 0.5f*(c2*(ud - tqi) - c3*Pdd);
        const float cF = cH + 0.5f*c2*ud - c1*qi;
        const float c1h = 0.5f * c1;
        Fx += cF*dx + c1*ux - c2*Pdx;
        Fy += cF*dy + c1*uy - c2*Pdy;
        Fz += cF*dz + c1*uz - c2*Pdz;
        Hx += cH*dx + c1h*ux - c2*Pdx;
        Hy += cH*dy + c1h*uy - c2*Pdy;
        Hz += cH*dz + c1h*uz - c2*Pdz;

        const float Rdx = jxx*dx + jxy*dy + jxz*dz;
        const float Rdy = jxy*dx + jyy*dy + jyz*dz;
        const float Rdz = jxz*dx + jyz*dy + jzz*dz;
        const float Rdd = Rdx*dx + Rdy*dy + Rdz*dz;
        const float dPR = Pdx*Rdx + Pdy*Rdy + Pdz*Rdz;
        const float frob = xx*jxx + yy*jyy + zz*jzz + 2.0f*(xy*jxy + xz*jxz + yz*jyz);
        pQQ += c4*(Pdd*Rdd)
             + c3*(jtq*Pdd + tqi*Rdd + 4.0f*dPR)
             + c2*(tqi*jtq + 2.0f*frob);
    }

    // ---- reduction: sum over segs; lanes 0..7 of each wave hold per-qch sums ----
    float acc[9] = {e0, eph, Fx, Fy, Fz, Hx, Hy, Hz, pQQ};
    #pragma unroll
    for (int off = 8; off < 64; off <<= 1) {
        #pragma unroll
        for (int c = 0; c < 9; ++c) acc[c] += __shfl_xor(acc[c], off, 64);
    }
    __shared__ float red[8][8][9];
    const int lane = tid & 63, wv = tid >> 6;   // 8 waves
    if ((lane & 56) == 0) {
        #pragma unroll
        for (int c = 0; c < 9; ++c) red[wv][lane][c] = acc[c];
    }
    __syncthreads();
    if (tid < 8) {
        float v[9];
        #pragma unroll
        for (int c = 0; c < 9; ++c) {
            float s = 0.f;
            #pragma unroll
            for (int w = 0; w < 8; ++w) s += red[w][tid][c];
            v[c] = s;
        }
        const float te0 = v[0], teph = v[1];
        const float tFx = v[2], tFy = v[3], tFz = v[4];
        const float tHx = v[5], tHy = v[6], tHz = v[7];
        const float tQQ = v[8] * 0.125f;
        const int myjq = j * NQC + tid;
        const float qj  = qarr[myjq];
        const float ujx = uarr[myjq*3+0], ujy = uarr[myjq*3+1], ujz = uarr[myjq*3+2];
        const float kapv = kaparr[myjq];
        const float alpv = alparr[myjq];

        float pot = qj * (teph - 0.5f*te0)
                  - (ujx*tHx + ujy*tHy + ujz*tHz)
                  + tQQ
                  - 0.5f * kapv * teph * teph
                  - 0.5f * alpv * (tFx*tFx + tFy*tFy + tFz*tFz);

        out[1 + myjq] = -kapv * teph;
        out[1 + NA*NQC + myjq*3 + 0] = alpv * tFx;
        out[1 + NA*NQC + myjq*3 + 1] = alpv * tFy;
        out[1 + NA*NQC + myjq*3 + 2] = alpv * tFz;

        // reduce pot across the 8 channels (lanes 0..7), one atomic per block
        #pragma unroll
        for (int off = 4; off; off >>= 1) pot += __shfl_xor(pot, off, 8);
        if (tid == 0) atomicAdd(out, pot);
    }
}

extern "C" void kernel_launch(void* const* d_in, const int* in_sizes, int n_in,
                              void* d_out, int out_size, void* d_ws, size_t ws_size,
                              hipStream_t stream) {
    const float* q    = (const float*)d_in[0];
    const float* r    = (const float*)d_in[1];
    const float* u    = (const float*)d_in[4];
    const float* quad = (const float*)d_in[5];
    const float* kap  = (const float*)d_in[6];
    const float* alp  = (const float*)d_in[7];
    float* out = (float*)d_out;
    float* ws  = (float*)d_ws;

    const size_t src_floats = (size_t)NA * NQC * SRC_STRIDE;   // 49152
    float*  ws_src = ws;
    float4* r4     = (float4*)(ws + src_floats);
    (void)ws_size; (void)in_sizes; (void)n_in; (void)out_size;

    pack_kernel<<<16, 256, 0, stream>>>(q, r, u, quad, ws_src, r4, out);
    main_kernel<<<NA, 512, 0, stream>>>(ws_src, r4, q, u, kap, alp, out);
}